// Round 1
// baseline (252.932 us; speedup 1.0000x reference)
//
#include <hip/hip_runtime.h>

// Interior pixel counts per scale
#define S1 254          // 256x256 -> 254x254 interior
#define S2 126
#define S3 62
#define T1 (S1*S1)      // 64516
#define T2 (S2*S2)      // 15876
#define T3 (S3*S3)      // 3844
#define TTOT (T1+T2+T3) // 84236

__device__ __forceinline__ void peak_check(const float* __restrict__ h, int W,
                                           int i, int j, int R,
                                           int& sy, int& sx, int& c) {
    const float* r0 = h + (i - 1) * W + j;
    const float* r1 = h + i * W + j;
    const float* r2 = h + (i + 1) * W + j;
    float v = r1[0];
    bool p = (v > r0[-1]) & (v > r0[0]) & (v > r0[1])
           & (v > r1[-1]) & (v > r1[1])
           & (v > r2[-1]) & (v > r2[0]) & (v > r2[1]);
    if (p) { sy += R * i; sx += R * j; c += 1; }
}

__device__ __forceinline__ int wave_reduce_i(int v) {
    #pragma unroll
    for (int o = 32; o > 0; o >>= 1) v += __shfl_down(v, o, 64);
    return v;
}

__global__ __launch_bounds__(256) void peaks_kernel(
    const float* __restrict__ p1, const float* __restrict__ p2,
    const float* __restrict__ p3, int* __restrict__ ws) {
    const int n   = blockIdx.y;
    const int pid = blockIdx.x * 256 + threadIdx.x;

    int sy = 0, sx = 0, c = 0;
    if (pid < T1) {
        int q = pid;
        int i = q / S1 + 1, j = q % S1 + 1;           // magic-mul (const divisor)
        const float* h = p1 + n * 196608 + 131072;    // n*3*65536 + 2*65536
        peak_check(h, 256, i, j, 4, sy, sx, c);
    } else if (pid < T1 + T2) {
        int q = pid - T1;
        int i = q / S2 + 1, j = q % S2 + 1;
        const float* h = p2 + n * 49152 + 32768;      // n*3*16384 + 2*16384
        peak_check(h, 128, i, j, 8, sy, sx, c);
    } else if (pid < TTOT) {
        int q = pid - (T1 + T2);
        int i = q / S3 + 1, j = q % S3 + 1;
        const float* h = p3 + n * 12288 + 8192;       // n*3*4096 + 2*4096
        peak_check(h, 64, i, j, 16, sy, sx, c);
    }

    sy = wave_reduce_i(sy);
    sx = wave_reduce_i(sx);
    c  = wave_reduce_i(c);

    __shared__ int smem[3][4];
    const int lane = threadIdx.x & 63, wid = threadIdx.x >> 6;
    if (lane == 0) { smem[0][wid] = sy; smem[1][wid] = sx; smem[2][wid] = c; }
    __syncthreads();
    if (threadIdx.x == 0) {
        int a = smem[0][0] + smem[0][1] + smem[0][2] + smem[0][3];
        int b = smem[1][0] + smem[1][1] + smem[1][2] + smem[1][3];
        int d = smem[2][0] + smem[2][1] + smem[2][2] + smem[2][3];
        if (a) atomicAdd(&ws[n], a);
        if (b) atomicAdd(&ws[64 + n], b);
        if (d) atomicAdd(&ws[128 + n], d);
    }
}

__global__ __launch_bounds__(64) void finalize_kernel(
    const int* __restrict__ ws, const float* __restrict__ target,
    float* __restrict__ out) {
    const int n = threadIdx.x;  // 0..63 = batch index, single wave

    const float csy = (float)ws[n];
    const float csx = (float)ws[64 + n];
    const int   cnt = ws[128 + n];

    // truths: target[n, 32, 5]; boxes = [:, :, :4]; centers = (b[2:4]+b[0:2])*0.5
    float ty = 0.f, tx = 0.f;
    const float* t = target + n * 160;
    #pragma unroll 8
    for (int k = 0; k < 32; k++) {
        ty += (t[k * 5 + 2] + t[k * 5 + 0]) * 0.5f;
        tx += (t[k * 5 + 3] + t[k * 5 + 1]) * 0.5f;
    }

    // smooth-L1 per-batch terms (pairing: center_sum[:,0] (y) with truths[:,0])
    float dy = fabsf(csy - ty);
    float dx = fabsf(csx - tx);
    double offx = (dy < 1.f) ? 0.5 * (double)dy * dy : (double)dy - 0.5;
    double offy = (dx < 1.f) ? 0.5 * (double)dx * dx : (double)dx - 0.5;

    double cy_t = csy, cx_t = csx, ty_t = ty, tx_t = tx, pcnt = cnt;

    #pragma unroll
    for (int o = 32; o > 0; o >>= 1) {
        offx += __shfl_down(offx, o, 64);
        offy += __shfl_down(offy, o, 64);
        cy_t += __shfl_down(cy_t, o, 64);
        cx_t += __shfl_down(cx_t, o, 64);
        ty_t += __shfl_down(ty_t, o, 64);
        tx_t += __shfl_down(tx_t, o, 64);
        pcnt += __shfl_down(pcnt, o, 64);
    }

    if (n == 0) {
        double sgnx = offx / fabs(offx);   // matches ref: off/|off| (NaN if 0)
        double sgny = offy / fabs(offy);
        double loss = (sgnx * (cy_t - ty_t) + sgny * (cx_t - tx_t)) / pcnt;
        out[0] = (float)loss;
    }
}

extern "C" void kernel_launch(void* const* d_in, const int* in_sizes, int n_in,
                              void* d_out, int out_size, void* d_ws, size_t ws_size,
                              hipStream_t stream) {
    const float* p1     = (const float*)d_in[0];
    const float* p2     = (const float*)d_in[1];
    const float* p3     = (const float*)d_in[2];
    const float* target = (const float*)d_in[3];
    float* out = (float*)d_out;
    int*   ws  = (int*)d_ws;

    // ws poisoned with 0xAA before every call — zero the 3*64 int accumulators.
    hipMemsetAsync(ws, 0, 3 * 64 * sizeof(int), stream);

    dim3 grid((TTOT + 255) / 256, 64);
    peaks_kernel<<<grid, 256, 0, stream>>>(p1, p2, p3, ws);
    finalize_kernel<<<1, 64, 0, stream>>>(ws, target, out);
}

// Round 2
// 104.194 us; speedup vs baseline: 2.4275x; 2.4275x over previous
//
#include <hip/hip_runtime.h>

// 4x4-pixel tiles per thread. Tiles-per-dim per scale:
#define G1 64   // H=W=256: interior 254 -> 64 tiles (last tile 2 rows/cols)
#define G2 32   // 128: interior 126
#define G3 16   // 64:  interior 62
#define TT1 (G1*G1)          // 4096
#define TT2 (G2*G2)          // 1024
#define TT3 (G3*G3)          // 256
#define TTOT (TT1+TT2+TT3)   // 5376  (= 21 blocks * 256)

template<int W>
__device__ __forceinline__ void load_row(const float* __restrict__ h, int r,
                                         int j0, bool fullj, float a[8]) {
    const float* p = h + r * W + (j0 - 1);   // j0-1 = 4*tx -> 16B aligned
    float4 lo = *(const float4*)p;
    a[0] = lo.x; a[1] = lo.y; a[2] = lo.z; a[3] = lo.w;
    float4 hi = make_float4(0.f, 0.f, 0.f, 0.f);
    if (fullj) hi = *(const float4*)(p + 4);
    a[4] = hi.x; a[5] = hi.y; a[6] = hi.z; a[7] = hi.w;
}

template<int W, int R>
__device__ __forceinline__ void do_tile(const float* __restrict__ h,
                                        int ty, int tx,
                                        int& sy, int& sx, int& cnt) {
    const int i0 = 1 + 4 * ty;
    const int j0 = 1 + 4 * tx;
    const int ilast = min(i0 + 3, W - 2);      // last tile: only 2 valid rows
    const bool fullj = (j0 + 3 <= W - 2);      // last strip: only 2 valid cols

    float a[3][8];
    load_row<W>(h, i0 - 1, j0, fullj, a[0]);
    load_row<W>(h, i0,     j0, fullj, a[1]);

    #pragma unroll
    for (int k = 0; k < 4; k++) {
        const int i = i0 + k;
        if (i <= ilast) {
            load_row<W>(h, i + 1, j0, fullj, a[(k + 2) % 3]);
            const float* top = a[k % 3];
            const float* mid = a[(k + 1) % 3];
            const float* bot = a[(k + 2) % 3];
            #pragma unroll
            for (int p = 0; p < 4; p++) {
                const float c = mid[p + 1];
                bool pk = (c > top[p]) & (c > top[p + 1]) & (c > top[p + 2])
                        & (c > mid[p]) & (c > mid[p + 2])
                        & (c > bot[p]) & (c > bot[p + 1]) & (c > bot[p + 2]);
                if (pk && (j0 + p <= W - 2)) {
                    sy += R * i; sx += R * (j0 + p); cnt++;
                }
            }
        }
    }
}

__device__ __forceinline__ int wave_reduce_i(int v) {
    #pragma unroll
    for (int o = 32; o > 0; o >>= 1) v += __shfl_down(v, o, 64);
    return v;
}

__global__ __launch_bounds__(256) void peaks_kernel(
    const float* __restrict__ p1, const float* __restrict__ p2,
    const float* __restrict__ p3, int* __restrict__ ws) {
    const int n   = blockIdx.y;
    const int pid = blockIdx.x * 256 + threadIdx.x;   // < 5376 exactly

    int sy = 0, sx = 0, c = 0;
    if (pid < TT1) {                                   // wave-uniform (4096 % 64 == 0)
        do_tile<256, 4>(p1 + n * 196608 + 131072, pid >> 6, pid & 63, sy, sx, c);
    } else if (pid < TT1 + TT2) {                      // 1024 % 64 == 0
        const int q = pid - TT1;
        do_tile<128, 8>(p2 + n * 49152 + 32768, q >> 5, q & 31, sy, sx, c);
    } else {                                           // 256 % 64 == 0
        const int q = pid - (TT1 + TT2);
        do_tile<64, 16>(p3 + n * 12288 + 8192, q >> 4, q & 15, sy, sx, c);
    }

    sy = wave_reduce_i(sy);
    sx = wave_reduce_i(sx);
    c  = wave_reduce_i(c);

    __shared__ int smem[3][4];
    const int lane = threadIdx.x & 63, wid = threadIdx.x >> 6;
    if (lane == 0) { smem[0][wid] = sy; smem[1][wid] = sx; smem[2][wid] = c; }
    __syncthreads();
    if (threadIdx.x == 0) {
        int a = smem[0][0] + smem[0][1] + smem[0][2] + smem[0][3];
        int b = smem[1][0] + smem[1][1] + smem[1][2] + smem[1][3];
        int d = smem[2][0] + smem[2][1] + smem[2][2] + smem[2][3];
        if (a) atomicAdd(&ws[n], a);
        if (b) atomicAdd(&ws[64 + n], b);
        if (d) atomicAdd(&ws[128 + n], d);
    }
}

__global__ __launch_bounds__(64) void finalize_kernel(
    const int* __restrict__ ws, const float* __restrict__ target,
    float* __restrict__ out) {
    const int n = threadIdx.x;  // 0..63 = batch index, single wave

    const float csy = (float)ws[n];
    const float csx = (float)ws[64 + n];
    const int   cnt = ws[128 + n];

    float ty = 0.f, tx = 0.f;
    const float* t = target + n * 160;
    #pragma unroll 8
    for (int k = 0; k < 32; k++) {
        ty += (t[k * 5 + 2] + t[k * 5 + 0]) * 0.5f;
        tx += (t[k * 5 + 3] + t[k * 5 + 1]) * 0.5f;
    }

    float dy = fabsf(csy - ty);
    float dx = fabsf(csx - tx);
    double offx = (dy < 1.f) ? 0.5 * (double)dy * dy : (double)dy - 0.5;
    double offy = (dx < 1.f) ? 0.5 * (double)dx * dx : (double)dx - 0.5;

    double cy_t = csy, cx_t = csx, ty_t = ty, tx_t = tx, pcnt = cnt;

    #pragma unroll
    for (int o = 32; o > 0; o >>= 1) {
        offx += __shfl_down(offx, o, 64);
        offy += __shfl_down(offy, o, 64);
        cy_t += __shfl_down(cy_t, o, 64);
        cx_t += __shfl_down(cx_t, o, 64);
        ty_t += __shfl_down(ty_t, o, 64);
        tx_t += __shfl_down(tx_t, o, 64);
        pcnt += __shfl_down(pcnt, o, 64);
    }

    if (n == 0) {
        double sgnx = offx / fabs(offx);
        double sgny = offy / fabs(offy);
        double loss = (sgnx * (cy_t - ty_t) + sgny * (cx_t - tx_t)) / pcnt;
        out[0] = (float)loss;
    }
}

extern "C" void kernel_launch(void* const* d_in, const int* in_sizes, int n_in,
                              void* d_out, int out_size, void* d_ws, size_t ws_size,
                              hipStream_t stream) {
    const float* p1     = (const float*)d_in[0];
    const float* p2     = (const float*)d_in[1];
    const float* p3     = (const float*)d_in[2];
    const float* target = (const float*)d_in[3];
    float* out = (float*)d_out;
    int*   ws  = (int*)d_ws;

    hipMemsetAsync(ws, 0, 3 * 64 * sizeof(int), stream);

    dim3 grid(TTOT / 256, 64);   // 21 x 64 blocks
    peaks_kernel<<<grid, 256, 0, stream>>>(p1, p2, p3, ws);
    finalize_kernel<<<1, 64, 0, stream>>>(ws, target, out);
}

// Round 3
// 102.196 us; speedup vs baseline: 2.4750x; 1.0196x over previous
//
#include <hip/hip_runtime.h>

// 4x4-pixel tiles per thread. Tiles-per-dim per scale:
#define G1 64   // H=W=256: interior 254 -> 64 tiles (last tile 2 rows/cols)
#define G2 32   // 128: interior 126
#define G3 16   // 64:  interior 62
#define TT1 (G1*G1)          // 4096 -> blocks 0..15
#define TT2 (G2*G2)          // 1024 -> blocks 16..19
#define TT3 (G3*G3)          // 256  -> block 20
#define TTOT (TT1+TT2+TT3)   // 5376 = 21 blocks * 256
#define NBLK 21
#define NBATCH 64
#define NPART (NBLK*NBATCH)  // 1344 partials per component

template<int W>
__device__ __forceinline__ void load_row(const float* __restrict__ h, int r,
                                         int j0, bool fullj, float a[8]) {
    const float* p = h + r * W + (j0 - 1);   // j0-1 = 4*tx -> 16B aligned
    float4 lo = *(const float4*)p;
    a[0] = lo.x; a[1] = lo.y; a[2] = lo.z; a[3] = lo.w;
    float4 hi = make_float4(0.f, 0.f, 0.f, 0.f);
    if (fullj) hi = *(const float4*)(p + 4);
    a[4] = hi.x; a[5] = hi.y; a[6] = hi.z; a[7] = hi.w;
}

template<int W, int R>
__device__ __forceinline__ void do_tile(const float* __restrict__ h,
                                        int ty, int tx,
                                        int& sy, int& sx, int& cnt) {
    const int i0 = 1 + 4 * ty;
    const int j0 = 1 + 4 * tx;
    const int ilast = min(i0 + 3, W - 2);      // last tile row: only 2 valid rows
    const bool fullj = (j0 + 3 <= W - 2);      // last strip: only 2 valid cols

    float a[3][8];
    load_row<W>(h, i0 - 1, j0, fullj, a[0]);
    load_row<W>(h, i0,     j0, fullj, a[1]);

    #pragma unroll
    for (int k = 0; k < 4; k++) {
        const int i = i0 + k;
        if (i <= ilast) {
            load_row<W>(h, i + 1, j0, fullj, a[(k + 2) % 3]);
            const float* top = a[k % 3];
            const float* mid = a[(k + 1) % 3];
            const float* bot = a[(k + 2) % 3];
            #pragma unroll
            for (int p = 0; p < 4; p++) {
                const float c = mid[p + 1];
                bool pk = (c > top[p]) & (c > top[p + 1]) & (c > top[p + 2])
                        & (c > mid[p]) & (c > mid[p + 2])
                        & (c > bot[p]) & (c > bot[p + 1]) & (c > bot[p + 2]);
                if (pk && (j0 + p <= W - 2)) {
                    sy += R * i; sx += R * (j0 + p); cnt++;
                }
            }
        }
    }
}

__device__ __forceinline__ int wave_reduce_i(int v) {
    #pragma unroll
    for (int o = 32; o > 0; o >>= 1) v += __shfl_down(v, o, 64);
    return v;
}

__global__ __launch_bounds__(256) void peaks_kernel(
    const float* __restrict__ p1, const float* __restrict__ p2,
    const float* __restrict__ p3, int* __restrict__ ws) {
    const int n   = blockIdx.y;
    const int bx  = blockIdx.x;
    const int pid = bx * 256 + threadIdx.x;   // < 5376 exactly

    int sy = 0, sx = 0, c = 0;
    if (pid < TT1) {                                   // blocks 0..15 (wave-uniform)
        do_tile<256, 4>(p1 + n * 196608 + 131072, pid >> 6, pid & 63, sy, sx, c);
    } else if (pid < TT1 + TT2) {                      // blocks 16..19
        const int q = pid - TT1;
        do_tile<128, 8>(p2 + n * 49152 + 32768, q >> 5, q & 31, sy, sx, c);
    } else {                                           // block 20
        const int q = pid - (TT1 + TT2);
        do_tile<64, 16>(p3 + n * 12288 + 8192, q >> 4, q & 15, sy, sx, c);
    }

    sy = wave_reduce_i(sy);
    sx = wave_reduce_i(sx);
    c  = wave_reduce_i(c);

    __shared__ int smem[3][4];
    const int lane = threadIdx.x & 63, wid = threadIdx.x >> 6;
    if (lane == 0) { smem[0][wid] = sy; smem[1][wid] = sx; smem[2][wid] = c; }
    __syncthreads();
    if (threadIdx.x == 0) {
        // Per-block partial write — no zero-init of ws required (poison-proof).
        const int slot = n * NBLK + bx;
        ws[slot]             = smem[0][0] + smem[0][1] + smem[0][2] + smem[0][3];
        ws[NPART + slot]     = smem[1][0] + smem[1][1] + smem[1][2] + smem[1][3];
        ws[2 * NPART + slot] = smem[2][0] + smem[2][1] + smem[2][2] + smem[2][3];
    }
}

__global__ __launch_bounds__(64) void finalize_kernel(
    const int* __restrict__ ws, const float* __restrict__ target,
    float* __restrict__ out) {
    const int n = threadIdx.x;  // 0..63 = batch index, single wave

    int isy = 0, isx = 0, cnt = 0;
    #pragma unroll
    for (int b = 0; b < NBLK; b++) {
        const int slot = n * NBLK + b;
        isy += ws[slot];
        isx += ws[NPART + slot];
        cnt += ws[2 * NPART + slot];
    }
    const float csy = (float)isy;
    const float csx = (float)isx;

    float ty = 0.f, tx = 0.f;
    const float* t = target + n * 160;
    #pragma unroll 8
    for (int k = 0; k < 32; k++) {
        ty += (t[k * 5 + 2] + t[k * 5 + 0]) * 0.5f;
        tx += (t[k * 5 + 3] + t[k * 5 + 1]) * 0.5f;
    }

    float dy = fabsf(csy - ty);
    float dx = fabsf(csx - tx);
    double offx = (dy < 1.f) ? 0.5 * (double)dy * dy : (double)dy - 0.5;
    double offy = (dx < 1.f) ? 0.5 * (double)dx * dx : (double)dx - 0.5;

    double cy_t = csy, cx_t = csx, ty_t = ty, tx_t = tx, pcnt = cnt;

    #pragma unroll
    for (int o = 32; o > 0; o >>= 1) {
        offx += __shfl_down(offx, o, 64);
        offy += __shfl_down(offy, o, 64);
        cy_t += __shfl_down(cy_t, o, 64);
        cx_t += __shfl_down(cx_t, o, 64);
        ty_t += __shfl_down(ty_t, o, 64);
        tx_t += __shfl_down(tx_t, o, 64);
        pcnt += __shfl_down(pcnt, o, 64);
    }

    if (n == 0) {
        double sgnx = offx / fabs(offx);
        double sgny = offy / fabs(offy);
        double loss = (sgnx * (cy_t - ty_t) + sgny * (cx_t - tx_t)) / pcnt;
        out[0] = (float)loss;
    }
}

extern "C" void kernel_launch(void* const* d_in, const int* in_sizes, int n_in,
                              void* d_out, int out_size, void* d_ws, size_t ws_size,
                              hipStream_t stream) {
    const float* p1     = (const float*)d_in[0];
    const float* p2     = (const float*)d_in[1];
    const float* p3     = (const float*)d_in[2];
    const float* target = (const float*)d_in[3];
    float* out = (float*)d_out;
    int*   ws  = (int*)d_ws;

    dim3 grid(NBLK, NBATCH);   // 21 x 64 blocks
    peaks_kernel<<<grid, 256, 0, stream>>>(p1, p2, p3, ws);
    finalize_kernel<<<1, 64, 0, stream>>>(ws, target, out);
}